// Round 10
// baseline (285.055 us; speedup 1.0000x reference)
//
#include <hip/hip_runtime.h>
#include <math.h>

typedef __bf16 bf16_t;
typedef __attribute__((ext_vector_type(8))) __bf16 bf16x8;
typedef __attribute__((ext_vector_type(4))) float f32x4;
typedef __attribute__((ext_vector_type(16))) float f32x16;

#define AS_G __attribute__((address_space(1)))
#define AS_L __attribute__((address_space(3)))

__device__ __forceinline__ f32x4 mfma16(bf16x8 a, bf16x8 b, f32x4 c) {
  return __builtin_amdgcn_mfma_f32_16x16x32_bf16(a, b, c, 0, 0, 0);
}
__device__ __forceinline__ f32x16 mfma32(bf16x8 a, bf16x8 b, f32x16 c) {
  return __builtin_amdgcn_mfma_f32_32x32x16_bf16(a, b, c, 0, 0, 0);
}

// async global->LDS, 16B per lane; LDS dest = wave-uniform base + lane*16
__device__ __forceinline__ void gload16(const bf16_t* g, bf16_t* l) {
  __builtin_amdgcn_global_load_lds((const AS_G void*)g, (AS_L void*)l, 16, 0, 0);
}

__global__ void cvt_f32_bf16_k(const float* __restrict__ in, bf16_t* __restrict__ out, int n4) {
  int i = blockIdx.x * blockDim.x + threadIdx.x;
  int stride = gridDim.x * blockDim.x;
  for (; i < n4; i += stride) {
    float4 v = reinterpret_cast<const float4*>(in)[i];
    union { bf16_t b[4]; short4 s; } u;
    u.b[0] = (bf16_t)v.x; u.b[1] = (bf16_t)v.y;
    u.b[2] = (bf16_t)v.z; u.b[3] = (bf16_t)v.w;
    reinterpret_cast<short4*>(out)[i] = u.s;
  }
}

// C = A(M x K, row) * B(N x K, row)^T.  128x128 tile, BK=32, 4 waves (2x2), m97 structure.
// EPI=0: scatter into Q (scaled 0.125*log2e -> exp2-domain softmax), K as [B,H,L,D] bf16;
//        V transposed as [B,H,D,L] bf16.
// EPI=1: plain fp32 row-major output.  (verified rounds 1/4/6/7 — scale const only change)
template <int EPI>
__global__ __launch_bounds__(256)
void gemm_bt(const bf16_t* __restrict__ A, const bf16_t* __restrict__ Bm,
             bf16_t* __restrict__ q_out, bf16_t* __restrict__ k_out,
             bf16_t* __restrict__ vt_out, float* __restrict__ f_out,
             int M, int N, int K) {
  __shared__ __align__(16) bf16_t lA[128 * 32];
  __shared__ __align__(16) bf16_t lB[128 * 32];
  const int lane = threadIdx.x & 63;
  const int wid = threadIdx.x >> 6;
  const int m0 = blockIdx.y * 128;
  const int n0 = blockIdx.x * 128;
  const int wr = (wid >> 1) * 64;
  const int wc = (wid & 1) * 64;
  const int lr = lane & 15;
  const int lg = lane >> 4;
  const int srow = lane >> 2;
  const int scol = (lane & 3) * 8;
  const int s0 = wid * 2, s1 = s0 + 1;

  f32x4 acc[4][4] = {};

  for (int k0 = 0; k0 < K; k0 += 32) {
    gload16(A + (size_t)(m0 + s0 * 16 + srow) * K + k0 + scol, &lA[s0 * 512]);
    gload16(A + (size_t)(m0 + s1 * 16 + srow) * K + k0 + scol, &lA[s1 * 512]);
    gload16(Bm + (size_t)(n0 + s0 * 16 + srow) * K + k0 + scol, &lB[s0 * 512]);
    gload16(Bm + (size_t)(n0 + s1 * 16 + srow) * K + k0 + scol, &lB[s1 * 512]);
    __syncthreads();
    bf16x8 af[4], bfr[4];
#pragma unroll
    for (int m = 0; m < 4; ++m)
      af[m] = *reinterpret_cast<const bf16x8*>(&lA[(wr + m * 16 + lr) * 32 + lg * 8]);
#pragma unroll
    for (int n = 0; n < 4; ++n)
      bfr[n] = *reinterpret_cast<const bf16x8*>(&lB[(wc + n * 16 + lr) * 32 + lg * 8]);
#pragma unroll
    for (int m = 0; m < 4; ++m)
#pragma unroll
      for (int n = 0; n < 4; ++n)
        acc[m][n] = mfma16(af[m], bfr[n], acc[m][n]);
    __syncthreads();
  }

  if (EPI == 0) {
#pragma unroll
    for (int n = 0; n < 4; ++n) {
      const int gn = n0 + wc + n * 16 + lr;
      const int sec = gn >> 10;
      const int hd = gn & 1023;
      const int h = hd >> 6, d = hd & 63;
#pragma unroll
      for (int m = 0; m < 4; ++m) {
        const int gm0 = m0 + wr + m * 16 + lg * 4;
        if (sec == 0) {
#pragma unroll
          for (int r = 0; r < 4; ++r) {
            const int gm = gm0 + r;
            // 1/sqrt(64) * log2(e): S comes out in log2 domain for exp2 softmax
            q_out[((size_t)((gm >> 11) * 16 + h) * 2048 + (gm & 2047)) * 64 + d] =
                (bf16_t)(acc[m][n][r] * 0.18033688f);
          }
        } else if (sec == 1) {
#pragma unroll
          for (int r = 0; r < 4; ++r) {
            const int gm = gm0 + r;
            k_out[((size_t)((gm >> 11) * 16 + h) * 2048 + (gm & 2047)) * 64 + d] =
                (bf16_t)acc[m][n][r];
          }
        } else {
          union { bf16_t b[4]; short4 s; } u;
#pragma unroll
          for (int r = 0; r < 4; ++r) u.b[r] = (bf16_t)acc[m][n][r];
          const int b = gm0 >> 11, sl = gm0 & 2047;
          *reinterpret_cast<short4*>(
              &vt_out[((size_t)(b * 16 + h) * 64 + d) * 2048 + sl]) = u.s;
        }
      }
    }
  } else {
#pragma unroll
    for (int m = 0; m < 4; ++m) {
      const int gm0 = m0 + wr + m * 16 + lg * 4;
#pragma unroll
      for (int n = 0; n < 4; ++n) {
        const int gn = n0 + wc + n * 16 + lr;
#pragma unroll
        for (int r = 0; r < 4; ++r)
          f_out[(size_t)(gm0 + r) * N + gn] = acc[m][n][r];
      }
    }
  }
}

// ---- per-tile attention compute (swapped-operand 32x32x16, verified rounds 6/7) ----
// S in log2 domain (Q pre-scaled by 0.125*log2e); exp2f softmax.
// lane owns q = q0w + (lane&31); holds S[q][k=32n+crow(r,hi)], crow=(r&3)+4*hi+8*(r>>2).
__device__ __forceinline__ void attn_tile(
    const bf16_t* __restrict__ tK, const bf16_t* __restrict__ tV,
    int kb, int q0w, int qrow, int q32, int hi,
    const bf16x8 bq[4], f32x16 oacc[2], float& m_run, float& l_run) {
  // ---- S^T = K . Q^T ----
  f32x16 sacc[2] = {};
#pragma unroll
  for (int n = 0; n < 2; ++n) {
    const int row = n * 32 + q32;
    const int rx = row & 7;
#pragma unroll
    for (int c = 0; c < 4; ++c) {
      bf16x8 ak = *reinterpret_cast<const bf16x8*>(
          &tK[row * 64 + ((2 * c + hi) ^ rx) * 8]);
      sacc[n] = mfma32(ak, bq[c], sacc[n]);
    }
  }
  // ---- causal mask (diagonal-region tiles only) ----
  if (kb + 63 > q0w) {
#pragma unroll
    for (int n = 0; n < 2; ++n)
#pragma unroll
      for (int r = 0; r < 16; ++r) {
        const int kg = kb + n * 32 + (r & 3) + 4 * hi + 8 * (r >> 2);
        if (kg > qrow) sacc[n][r] = -1e30f;
      }
  }
  // ---- row max: in-lane tree + 1 cross-half shuffle ----
  float v8[8];
#pragma unroll
  for (int i = 0; i < 8; ++i)
    v8[i] = fmaxf(fmaxf(sacc[0][i], sacc[0][i + 8]),
                  fmaxf(sacc[1][i], sacc[1][i + 8]));
  float pm = fmaxf(fmaxf(fmaxf(v8[0], v8[4]), fmaxf(v8[1], v8[5])),
                   fmaxf(fmaxf(v8[2], v8[6]), fmaxf(v8[3], v8[7])));
  pm = fmaxf(pm, __shfl_xor(pm, 32));
  // ---- defer-max rescale (T13, THR=8 in log2 units -> P bounded by 256) ----
  if (__any(pm > m_run + 8.f)) {
    const float mn = fmaxf(m_run, pm);
    const float al = exp2f(m_run - mn);
#pragma unroll
    for (int ms = 0; ms < 2; ++ms)
#pragma unroll
      for (int r = 0; r < 16; ++r) oacc[ms][r] *= al;
    l_run *= al;
    m_run = mn;
  }
  // ---- exp2 + row sum ----
  float ls = 0.f;
#pragma unroll
  for (int n = 0; n < 2; ++n)
#pragma unroll
    for (int r = 0; r < 16; ++r) {
      const float p = exp2f(sacc[n][r] - m_run);
      sacc[n][r] = p;
      ls += p;
    }
  ls += __shfl_xor(ls, 32);
  l_run += ls;
  // ---- pack P to bf16 + redistribute to B-frag k-major layout ----
  bf16x8 pb[4];
#pragma unroll
  for (int n = 0; n < 2; ++n) {
    int w[8], pw[8];
#pragma unroll
    for (int j = 0; j < 8; ++j) {
      union { bf16_t b[2]; int i; } u;
      u.b[0] = (bf16_t)sacc[n][2 * j];
      u.b[1] = (bf16_t)sacc[n][2 * j + 1];
      w[j] = u.i;
    }
#pragma unroll
    for (int j = 0; j < 8; ++j) pw[j] = __shfl_xor(w[j], 32);
#pragma unroll
    for (int s = 0; s < 2; ++s) {
      union { int i[4]; bf16x8 v; } pv;
      if (hi == 0) {
        pv.i[0] = w[4 * s];      pv.i[1] = w[4 * s + 1];
        pv.i[2] = pw[4 * s];     pv.i[3] = pw[4 * s + 1];
      } else {
        pv.i[0] = pw[4 * s + 2]; pv.i[1] = pw[4 * s + 3];
        pv.i[2] = w[4 * s + 2];  pv.i[3] = w[4 * s + 3];
      }
      pb[2 * n + s] = pv.v;
    }
  }
  // ---- PV: O^T += Vt . P^T ----
#pragma unroll
  for (int s4 = 0; s4 < 4; ++s4) {
#pragma unroll
    for (int ms = 0; ms < 2; ++ms) {
      const int row = ms * 32 + q32;
      bf16x8 av = *reinterpret_cast<const bf16x8*>(
          &tV[row * 64 + ((2 * s4 + hi) ^ (row & 7)) * 8]);
      oacc[ms] = mfma32(av, pb[s4], oacc[ms]);
    }
  }
}

__device__ __forceinline__ void attn_epi(bf16_t* __restrict__ ctx, int bh,
                                         int qrow, int hi,
                                         const f32x16 oacc[2], float l_run) {
  const float inv = 1.f / l_run;
  const int b = bh >> 4, h = bh & 15;
  const size_t orow = (size_t)(b * 2048 + qrow) * 1024 + h * 64;
#pragma unroll
  for (int ms = 0; ms < 2; ++ms)
#pragma unroll
    for (int rg = 0; rg < 4; ++rg) {
      union { bf16_t b4[4]; short4 s; } u;
#pragma unroll
      for (int i = 0; i < 4; ++i) u.b4[i] = (bf16_t)(oacc[ms][rg * 4 + i] * inv);
      *reinterpret_cast<short4*>(&ctx[orow + ms * 32 + rg * 8 + hi * 4]) = u.s;
    }
}

// Flash attention, causal — paired q-tiles, 8-wave blocks for 2x residency.
// 512 blocks x 512 thr; waves 0-3 own q-tile jA=15-p (long), waves 4-7 own jB=p (short).
// Each wave: ONE 32-row state (single sacc/oacc/bq -> VGPR fits 128, 16 waves/CU).
// K/V staged once per block: waves 0-3 stage K, waves 4-7 stage V. Per-SIMD work
// = (2jA+2)+(2jB+2) = 36 tile-computes for every p -> perfect balance, zero tail.
__global__ __launch_bounds__(512, 4)
void attn_fwd(const bf16_t* __restrict__ Q, const bf16_t* __restrict__ Km,
              const bf16_t* __restrict__ Vt, bf16_t* __restrict__ ctx, int L) {
  __shared__ __align__(16) bf16_t lK[2][64 * 64];
  __shared__ __align__(16) bf16_t lV[2][64 * 64];

  const int lane = threadIdx.x & 63;
  const int wid = threadIdx.x >> 6;
  const int w4 = wid & 3;
  const int grp = wid >> 2;  // 0: A-state (jA), 1: B-state (jB)
  // XCD swizzle (512 blocks): XCD x gets bh in [x*8, x*8+8) = 4MB K/V (L2-fit).
  const int nid = (blockIdx.x & 7) * 64 + (blockIdx.x >> 3);
  const int bh = nid >> 3;
  const int p = nid & 7;
  const int jA = 15 - p, jB = p;
  const int q32 = lane & 31;
  const int hi = lane >> 5;
  const int j = grp ? jB : jA;
  const int q0 = j * 128 + w4 * 32;      // wave's 32-row state start (head-local)
  const int qrow = q0 + q32;             // lane's q-row
  const bf16_t* Qh = Q + (size_t)bh * L * 64;
  const bf16_t* Kh = Km + (size_t)bh * L * 64;
  const bf16_t* Vh = Vt + (size_t)bh * 64 * L;

  // Q B-fragments: bq[c] = Q[qrow][c*16 + hi*8 + j]
  bf16x8 bq[4];
#pragma unroll
  for (int c = 0; c < 4; ++c)
    bq[c] = *reinterpret_cast<const bf16x8*>(&Qh[(size_t)qrow * 64 + c * 16 + hi * 8]);

  f32x16 oacc[2] = {};
  float m_run = -1e30f, l_run = 0.f;

  // staging: K by waves 0-3, V by waves 4-7; each wave 2 gload16 rounds
  const int sr0 = w4 * 8 + (lane >> 3);
  const int sc = ((lane & 7) ^ (sr0 & 7)) * 8;  // inverse-swizzled src col (elems)
  const int nt = 2 * jA + 2;

#define STAGE(buf, kb)                                                        \
  do {                                                                        \
    if (grp == 0) {                                                           \
      gload16(Kh + (size_t)((kb) + sr0) * 64 + sc, &lK[buf][w4 * 512]);       \
      gload16(Kh + (size_t)((kb) + sr0 + 32) * 64 + sc,                       \
              &lK[buf][2048 + w4 * 512]);                                     \
    } else {                                                                  \
      gload16(Vh + (size_t)sr0 * L + (kb) + sc, &lV[buf][w4 * 512]);          \
      gload16(Vh + (size_t)(sr0 + 32) * L + (kb) + sc,                        \
              &lV[buf][2048 + w4 * 512]);                                     \
    }                                                                         \
  } while (0)

  STAGE(0, 0);
  int cur = 0;
  for (int t = 0; t < nt; ++t) {
    __syncthreads();  // implicit vmcnt(0): buf[cur] ready; prev reads of buf[cur^1] done
    if (t + 1 < nt) STAGE(cur ^ 1, (t + 1) * 64);
    const int kb = t * 64;
    if (kb <= q0 + 31)
      attn_tile(lK[cur], lV[cur], kb, q0, qrow, q32, hi, bq, oacc, m_run, l_run);
    cur ^= 1;
  }
#undef STAGE
  attn_epi(ctx, bh, qrow, hi, oacc, l_run);
}

extern "C" void kernel_launch(void* const* d_in, const int* in_sizes, int n_in,
                              void* d_out, int out_size, void* d_ws, size_t ws_size,
                              hipStream_t stream) {
  (void)in_sizes; (void)n_in; (void)out_size; (void)ws_size;
  const float* x     = (const float*)d_in[0];   // [4,2048,1024]
  const float* w_in  = (const float*)d_in[1];   // [3072,1024]
  const float* w_out = (const float*)d_in[2];   // [1024,1024]
  float* out = (float*)d_out;

  char* ws = (char*)d_ws;
  bf16_t* xb   = (bf16_t*)(ws);                         // 8388608 elems
  bf16_t* wib  = (bf16_t*)(ws + 16777216);              // 3145728
  bf16_t* wob  = (bf16_t*)(ws + 23068672);              // 1048576
  bf16_t* Qb   = (bf16_t*)(ws + 25165824);              // [B,H,L,D] (log2-scaled)
  bf16_t* Kb   = (bf16_t*)(ws + 41943040);              // [B,H,L,D]
  bf16_t* Vtb  = (bf16_t*)(ws + 58720256);              // [B,H,D,L]
  bf16_t* ctxb = (bf16_t*)(ws + 75497472);              // [B,L,C]

  const int M = 8192, C = 1024, L = 2048;

  {
    int n4 = 8388608 / 4, blk = (n4 + 255) / 256; if (blk > 2048) blk = 2048;
    cvt_f32_bf16_k<<<blk, 256, 0, stream>>>(x, xb, n4);
  }
  {
    int n4 = 3145728 / 4, blk = (n4 + 255) / 256; if (blk > 2048) blk = 2048;
    cvt_f32_bf16_k<<<blk, 256, 0, stream>>>(w_in, wib, n4);
  }
  {
    int n4 = 1048576 / 4, blk = (n4 + 255) / 256; if (blk > 2048) blk = 2048;
    cvt_f32_bf16_k<<<blk, 256, 0, stream>>>(w_out, wob, n4);
  }

  gemm_bt<0><<<dim3(3072 / 128, M / 128), 256, 0, stream>>>(
      xb, wib, Qb, Kb, Vtb, nullptr, M, 3072, C);

  attn_fwd<<<512, 512, 0, stream>>>(Qb, Kb, Vtb, ctxb, L);

  gemm_bt<1><<<dim3(C / 128, M / 128), 256, 0, stream>>>(
      ctxb, wob, nullptr, nullptr, nullptr, out, M, C, C);
}